// Round 9
// baseline (513.783 us; speedup 1.0000x reference)
//
#include <hip/hip_runtime.h>
#include <hip/hip_fp16.h>

#define THREADS 256

// ---------------- preprocessing ----------------

__global__ void k_count_dst(const int* __restrict__ ei, int* __restrict__ cnt, int E) {
    int e = blockIdx.x * blockDim.x + threadIdx.x;
    if (e < E) atomicAdd(&cnt[ei[E + e]], 1);
}

__global__ void k_count_src(const int* __restrict__ ei, int* __restrict__ cnt, int E) {
    int e = blockIdx.x * blockDim.x + threadIdx.x;
    if (e < E) atomicAdd(&cnt[ei[e]], 1);
}

__global__ void k_dinv(const int* __restrict__ cnt, float* __restrict__ dinv, int N) {
    int n = blockIdx.x * blockDim.x + threadIdx.x;
    if (n < N) dinv[n] = rsqrtf((float)cnt[n] + 1.0f);  // +1 self loop
}

__global__ void k_scan1(const int* __restrict__ cnt, int* __restrict__ rp,
                        int* __restrict__ bsum, int N) {
    __shared__ int s[THREADS];
    int tid = threadIdx.x;
    int i = blockIdx.x * THREADS + tid;
    int v = (i < N) ? cnt[i] : 0;
    s[tid] = v;
    __syncthreads();
    for (int d = 1; d < THREADS; d <<= 1) {
        int t = (tid >= d) ? s[tid - d] : 0;
        __syncthreads();
        s[tid] += t;
        __syncthreads();
    }
    if (i < N) rp[i] = s[tid] - v;
    if (tid == THREADS - 1) bsum[blockIdx.x] = s[tid];
}

__global__ void k_scan2(int* __restrict__ bsum, int nb) {
    __shared__ int s[THREADS];
    int tid = threadIdx.x;
    int v = (tid < nb) ? bsum[tid] : 0;
    s[tid] = v;
    __syncthreads();
    for (int d = 1; d < THREADS; d <<= 1) {
        int t = (tid >= d) ? s[tid - d] : 0;
        __syncthreads();
        s[tid] += t;
        __syncthreads();
    }
    if (tid < nb) bsum[tid] = s[tid] - v;
}

__global__ void k_add(int* __restrict__ rp, const int* __restrict__ bsum, int N, int E) {
    int i = blockIdx.x * THREADS + threadIdx.x;
    if (i < N) rp[i] += bsum[blockIdx.x];
    if (i == 0) rp[N] = E;
}

// dst-CSR position per original edge
__global__ void k_scatter_d(const int* __restrict__ ei, const int* __restrict__ rp,
                            int* __restrict__ fill, int* __restrict__ dpos, int E) {
    int e = blockIdx.x * blockDim.x + threadIdx.x;
    if (e >= E) return;
    int d = ei[E + e];
    dpos[e] = rp[d] + atomicAdd(&fill[d], 1);
}

// src-CSR entries: (dst-order position, weight)
__global__ void k_scatter_s(const int* __restrict__ ei, const int* __restrict__ srp,
                            int* __restrict__ fill, const float* __restrict__ dinv,
                            const int* __restrict__ dpos, int2* __restrict__ sdata, int E) {
    int e = blockIdx.x * blockDim.x + threadIdx.x;
    if (e >= E) return;
    int s = ei[e], d = ei[E + e];
    int sp = srp[s] + atomicAdd(&fill[s], 1);
    int2 q;
    q.x = dpos[e];
    q.y = __float_as_int(dinv[s] * dinv[d]);
    sdata[sp] = q;
}

// fallback path edge packets (R8)
__global__ void k_scatter_e(const int* __restrict__ ei, const int* __restrict__ rp,
                            int* __restrict__ fill, const float* __restrict__ dinv,
                            int2* __restrict__ epack, int E) {
    int e = blockIdx.x * blockDim.x + threadIdx.x;
    if (e >= E) return;
    int s = ei[e], d = ei[E + e];
    int pos = rp[d] + atomicAdd(&fill[d], 1);
    int2 p;
    p.x = s;
    p.y = __float_as_int(dinv[s] * dinv[d]);
    epack[pos] = p;
}

// ---------------- group sizes (sorted batch, no atomics) ----------------

__global__ void k_ginit(int* __restrict__ gstart, int N, int G) {
    int g = threadIdx.x;
    if (g < G) gstart[g] = N;
}

__global__ void k_gbound(const int* __restrict__ batch, int* __restrict__ gstart, int N) {
    int n = blockIdx.x * blockDim.x + threadIdx.x;
    if (n >= N) return;
    if (n == 0) gstart[batch[0]] = 0;
    else if (batch[n] != batch[n - 1]) gstart[batch[n]] = n;
}

__global__ void k_gfix(const int* __restrict__ gstart, float* __restrict__ gcnt, int N, int G) {
    __shared__ int s[129];
    int g = threadIdx.x;
    s[g] = gstart[g];
    if (g == 0) s[128] = N;
    __syncthreads();
    for (int d = 1; d < 128; d <<= 1) {
        int v = s[g];
        int w = (g + d <= 128) ? s[g + d] : N;
        __syncthreads();
        s[g] = min(v, w);
        __syncthreads();
    }
    int nxt = (g < 127) ? s[g + 1] : N;
    gcnt[g] = (float)(nxt - s[g]);
}

// ---------------- fp32 GEMM + fp16 mirror ----------------

#define BM 64
#define BK 32

__global__ __launch_bounds__(256) void k_gemm(const float* __restrict__ X,
                                              const float* __restrict__ W,
                                              float* __restrict__ Y,
                                              __half* __restrict__ Yh, int N) {
    __shared__ float Xs[BK][BM + 1];
    __shared__ float Ws[BK][128];
    int tid = threadIdx.x;
    int tr = tid & 15, tc = tid >> 4;
    int r0 = tr * 4, c0 = tc * 8;
    int m0 = blockIdx.x * BM;

    float acc[4][8];
#pragma unroll
    for (int r = 0; r < 4; ++r)
#pragma unroll
        for (int c = 0; c < 8; ++c) acc[r][c] = 0.f;

    for (int k0 = 0; k0 < 128; k0 += BK) {
        __syncthreads();
#pragma unroll
        for (int i = 0; i < 2; ++i) {
            int idx = tid + 256 * i;
            int row = idx >> 3;
            int kq  = idx & 7;
            float4 v = make_float4(0.f, 0.f, 0.f, 0.f);
            int grow = m0 + row;
            if (grow < N) v = *(const float4*)&X[(size_t)grow * 128 + k0 + kq * 4];
            Xs[kq * 4 + 0][row] = v.x;
            Xs[kq * 4 + 1][row] = v.y;
            Xs[kq * 4 + 2][row] = v.z;
            Xs[kq * 4 + 3][row] = v.w;
        }
#pragma unroll
        for (int i = 0; i < 4; ++i) {
            int idx = tid + 256 * i;
            int krow = idx >> 5;
            int cq   = idx & 31;
            *(float4*)&Ws[krow][cq * 4] = *(const float4*)&W[(size_t)(k0 + krow) * 128 + cq * 4];
        }
        __syncthreads();

#pragma unroll
        for (int kk = 0; kk < BK; ++kk) {
            float4 a  = *(const float4*)&Xs[kk][r0];
            float4 b0 = *(const float4*)&Ws[kk][c0];
            float4 b1 = *(const float4*)&Ws[kk][c0 + 4];
            float av[4] = {a.x, a.y, a.z, a.w};
            float bv[8] = {b0.x, b0.y, b0.z, b0.w, b1.x, b1.y, b1.z, b1.w};
#pragma unroll
            for (int r = 0; r < 4; ++r)
#pragma unroll
                for (int c = 0; c < 8; ++c)
                    acc[r][c] = fmaf(av[r], bv[c], acc[r][c]);
        }
    }

#pragma unroll
    for (int r = 0; r < 4; ++r) {
        int row = m0 + r0 + r;
        if (row < N) {
            float4 o0 = make_float4(acc[r][0], acc[r][1], acc[r][2], acc[r][3]);
            float4 o1 = make_float4(acc[r][4], acc[r][5], acc[r][6], acc[r][7]);
            *(float4*)&Y[(size_t)row * 128 + c0]     = o0;
            *(float4*)&Y[(size_t)row * 128 + c0 + 4] = o1;
            __half hbuf[8];
#pragma unroll
            for (int c = 0; c < 8; ++c) hbuf[c] = __float2half(acc[r][c]);
            *(int4*)&Yh[(size_t)row * 128 + c0] = *(int4*)hbuf;
        }
    }
}

// ---------------- Phase A: src-major scatter of weighted rows ----------------
// wave = src node; row held in regs; per out-edge: store w*row (fp16, 256B)
// to eval[dst_pos]. Random writes are fire-and-forget. Uniform-branch tail.

__global__ __launch_bounds__(256) void k_phaseA(const __half* __restrict__ Hh,
                                                const int* __restrict__ srp,
                                                const int2* __restrict__ sdata,
                                                __half* __restrict__ eval, int N) {
    int wid  = threadIdx.x >> 6;
    int lane = threadIdx.x & 63;
    int n = blockIdx.x * 4 + wid;
    if (n >= N) return;
    int c0 = lane * 2;
    float2 rf = __half22float2(*(const __half2*)&Hh[(size_t)n * 128 + c0]);

    int beg = srp[n], end = srp[n + 1];
    int last = end - 1;
    for (int e = beg; e < end; e += 8) {
        int2 q0 = sdata[e];
        int2 q1 = sdata[min(e + 1, last)];
        int2 q2 = sdata[min(e + 2, last)];
        int2 q3 = sdata[min(e + 3, last)];
        int2 q4 = sdata[min(e + 4, last)];
        int2 q5 = sdata[min(e + 5, last)];
        int2 q6 = sdata[min(e + 6, last)];
        int2 q7 = sdata[min(e + 7, last)];
        {
            float w = __int_as_float(q0.y);
            *(__half2*)&eval[(size_t)q0.x * 128 + c0] = __floats2half2_rn(w * rf.x, w * rf.y);
        }
        if (e + 1 < end) { float w = __int_as_float(q1.y); *(__half2*)&eval[(size_t)q1.x * 128 + c0] = __floats2half2_rn(w * rf.x, w * rf.y); }
        if (e + 2 < end) { float w = __int_as_float(q2.y); *(__half2*)&eval[(size_t)q2.x * 128 + c0] = __floats2half2_rn(w * rf.x, w * rf.y); }
        if (e + 3 < end) { float w = __int_as_float(q3.y); *(__half2*)&eval[(size_t)q3.x * 128 + c0] = __floats2half2_rn(w * rf.x, w * rf.y); }
        if (e + 4 < end) { float w = __int_as_float(q4.y); *(__half2*)&eval[(size_t)q4.x * 128 + c0] = __floats2half2_rn(w * rf.x, w * rf.y); }
        if (e + 5 < end) { float w = __int_as_float(q5.y); *(__half2*)&eval[(size_t)q5.x * 128 + c0] = __floats2half2_rn(w * rf.x, w * rf.y); }
        if (e + 6 < end) { float w = __int_as_float(q6.y); *(__half2*)&eval[(size_t)q6.x * 128 + c0] = __floats2half2_rn(w * rf.x, w * rf.y); }
        if (e + 7 < end) { float w = __int_as_float(q7.y); *(__half2*)&eval[(size_t)q7.x * 128 + c0] = __floats2half2_rn(w * rf.x, w * rf.y); }
    }
}

// ---------------- Phase B: dst-major streaming reduce ----------------
// wave = dst node; its edge values are contiguous [rp[n],rp[n+1]) -> pure
// streaming reads, no address dependency. + fp32 self-term + bias + relu.

template <int POOL>
__global__ __launch_bounds__(256) void k_phaseB(const float* __restrict__ H,
                                                const __half* __restrict__ eval,
                                                float* __restrict__ OUT,
                                                const int* __restrict__ rp,
                                                const float* __restrict__ dinv,
                                                const float* __restrict__ bias,
                                                const int* __restrict__ batch,
                                                float* __restrict__ pooled, int N) {
    int wid  = threadIdx.x >> 6;
    int lane = threadIdx.x & 63;
    int n = blockIdx.x * 4 + wid;
    if (n >= N) return;
    int c0 = lane * 2;

    float2 acc = make_float2(0.f, 0.f);
    int beg = rp[n], end = rp[n + 1];
    int last = end - 1;

    for (int e = beg; e < end; e += 8) {
        __half2 v0 = *(const __half2*)&eval[(size_t)e * 128 + c0];
        __half2 v1 = *(const __half2*)&eval[(size_t)min(e + 1, last) * 128 + c0];
        __half2 v2 = *(const __half2*)&eval[(size_t)min(e + 2, last) * 128 + c0];
        __half2 v3 = *(const __half2*)&eval[(size_t)min(e + 3, last) * 128 + c0];
        __half2 v4 = *(const __half2*)&eval[(size_t)min(e + 4, last) * 128 + c0];
        __half2 v5 = *(const __half2*)&eval[(size_t)min(e + 5, last) * 128 + c0];
        __half2 v6 = *(const __half2*)&eval[(size_t)min(e + 6, last) * 128 + c0];
        __half2 v7 = *(const __half2*)&eval[(size_t)min(e + 7, last) * 128 + c0];
        float m1 = (e + 1 < end) ? 1.f : 0.f;
        float m2 = (e + 2 < end) ? 1.f : 0.f;
        float m3 = (e + 3 < end) ? 1.f : 0.f;
        float m4 = (e + 4 < end) ? 1.f : 0.f;
        float m5 = (e + 5 < end) ? 1.f : 0.f;
        float m6 = (e + 6 < end) ? 1.f : 0.f;
        float m7 = (e + 7 < end) ? 1.f : 0.f;
        float2 f;
        f = __half22float2(v0); acc.x += f.x;             acc.y += f.y;
        f = __half22float2(v1); acc.x = fmaf(m1, f.x, acc.x); acc.y = fmaf(m1, f.y, acc.y);
        f = __half22float2(v2); acc.x = fmaf(m2, f.x, acc.x); acc.y = fmaf(m2, f.y, acc.y);
        f = __half22float2(v3); acc.x = fmaf(m3, f.x, acc.x); acc.y = fmaf(m3, f.y, acc.y);
        f = __half22float2(v4); acc.x = fmaf(m4, f.x, acc.x); acc.y = fmaf(m4, f.y, acc.y);
        f = __half22float2(v5); acc.x = fmaf(m5, f.x, acc.x); acc.y = fmaf(m5, f.y, acc.y);
        f = __half22float2(v6); acc.x = fmaf(m6, f.x, acc.x); acc.y = fmaf(m6, f.y, acc.y);
        f = __half22float2(v7); acc.x = fmaf(m7, f.x, acc.x); acc.y = fmaf(m7, f.y, acc.y);
    }

    float di = dinv[n];
    float sw = di * di;
    float2 hv = *(const float2*)&H[(size_t)n * 128 + c0];
    acc.x = fmaf(sw, hv.x, acc.x);
    acc.y = fmaf(sw, hv.y, acc.y);
    acc.x = fmaxf(acc.x + bias[c0], 0.f);
    acc.y = fmaxf(acc.y + bias[c0 + 1], 0.f);

    if (POOL) {
        int g = batch[n];
        atomicAdd(&pooled[g * 128 + c0], acc.x);
        atomicAdd(&pooled[g * 128 + c0 + 1], acc.y);
    } else {
        float2 o; o.x = acc.x; o.y = acc.y;
        *(float2*)&OUT[(size_t)n * 128 + c0] = o;
    }
}

// ---------------- fallback aggregation (R8, proven) ----------------

template <int POOL>
__global__ __launch_bounds__(256) void k_aggregate(const float* __restrict__ H,
                                                   const __half* __restrict__ Hh,
                                                   float* __restrict__ OUT,
                                                   const int* __restrict__ rp,
                                                   const int2* __restrict__ epack,
                                                   const float* __restrict__ dinv,
                                                   const float* __restrict__ bias,
                                                   const int* __restrict__ batch,
                                                   float* __restrict__ pooled, int N) {
    int wid  = threadIdx.x >> 6;
    int lane = threadIdx.x & 63;
    int n = blockIdx.x * 4 + wid;
    if (n >= N) return;
    int c0 = lane * 2;

    float2 acc = make_float2(0.f, 0.f);
    int beg = rp[n], end = rp[n + 1];
    int last = end - 1;

    for (int e = beg; e < end; e += 8) {
        int2 p0 = epack[e];
        int2 p1 = epack[min(e + 1, last)];
        int2 p2 = epack[min(e + 2, last)];
        int2 p3 = epack[min(e + 3, last)];
        int2 p4 = epack[min(e + 4, last)];
        int2 p5 = epack[min(e + 5, last)];
        int2 p6 = epack[min(e + 6, last)];
        int2 p7 = epack[min(e + 7, last)];
        float w0 = __int_as_float(p0.y);
        float w1 = (e + 1 < end) ? __int_as_float(p1.y) : 0.f;
        float w2 = (e + 2 < end) ? __int_as_float(p2.y) : 0.f;
        float w3 = (e + 3 < end) ? __int_as_float(p3.y) : 0.f;
        float w4 = (e + 4 < end) ? __int_as_float(p4.y) : 0.f;
        float w5 = (e + 5 < end) ? __int_as_float(p5.y) : 0.f;
        float w6 = (e + 6 < end) ? __int_as_float(p6.y) : 0.f;
        float w7 = (e + 7 < end) ? __int_as_float(p7.y) : 0.f;
        __half2 h0 = *(const __half2*)&Hh[(size_t)p0.x * 128 + c0];
        __half2 h1 = *(const __half2*)&Hh[(size_t)p1.x * 128 + c0];
        __half2 h2 = *(const __half2*)&Hh[(size_t)p2.x * 128 + c0];
        __half2 h3 = *(const __half2*)&Hh[(size_t)p3.x * 128 + c0];
        __half2 h4 = *(const __half2*)&Hh[(size_t)p4.x * 128 + c0];
        __half2 h5 = *(const __half2*)&Hh[(size_t)p5.x * 128 + c0];
        __half2 h6 = *(const __half2*)&Hh[(size_t)p6.x * 128 + c0];
        __half2 h7 = *(const __half2*)&Hh[(size_t)p7.x * 128 + c0];
        float2 f;
        f = __half22float2(h0); acc.x = fmaf(w0, f.x, acc.x); acc.y = fmaf(w0, f.y, acc.y);
        f = __half22float2(h1); acc.x = fmaf(w1, f.x, acc.x); acc.y = fmaf(w1, f.y, acc.y);
        f = __half22float2(h2); acc.x = fmaf(w2, f.x, acc.x); acc.y = fmaf(w2, f.y, acc.y);
        f = __half22float2(h3); acc.x = fmaf(w3, f.x, acc.x); acc.y = fmaf(w3, f.y, acc.y);
        f = __half22float2(h4); acc.x = fmaf(w4, f.x, acc.x); acc.y = fmaf(w4, f.y, acc.y);
        f = __half22float2(h5); acc.x = fmaf(w5, f.x, acc.x); acc.y = fmaf(w5, f.y, acc.y);
        f = __half22float2(h6); acc.x = fmaf(w6, f.x, acc.x); acc.y = fmaf(w6, f.y, acc.y);
        f = __half22float2(h7); acc.x = fmaf(w7, f.x, acc.x); acc.y = fmaf(w7, f.y, acc.y);
    }

    float di = dinv[n];
    float sw = di * di;
    float2 hv = *(const float2*)&H[(size_t)n * 128 + c0];
    acc.x = fmaf(sw, hv.x, acc.x);
    acc.y = fmaf(sw, hv.y, acc.y);
    acc.x = fmaxf(acc.x + bias[c0], 0.f);
    acc.y = fmaxf(acc.y + bias[c0 + 1], 0.f);

    if (POOL) {
        int g = batch[n];
        atomicAdd(&pooled[g * 128 + c0], acc.x);
        atomicAdd(&pooled[g * 128 + c0 + 1], acc.y);
    } else {
        float2 o; o.x = acc.x; o.y = acc.y;
        *(float2*)&OUT[(size_t)n * 128 + c0] = o;
    }
}

// ---------------- final ----------------

__global__ void k_final(const float* __restrict__ pooled, const float* __restrict__ gcnt,
                        const float* __restrict__ lw, const float* __restrict__ lb,
                        float* __restrict__ out, int G) {
    int i = blockIdx.x * blockDim.x + threadIdx.x;
    if (i >= G * 64) return;
    int g = i >> 6, o = i & 63;
    float inv = 1.0f / fmaxf(gcnt[g], 1.0f);
    float acc = 0.f;
#pragma unroll
    for (int k = 0; k < 128; ++k) acc = fmaf(pooled[g * 128 + k], lw[k * 64 + o], acc);
    out[i] = acc * inv + lb[o];
}

// ---------------- launch ----------------

extern "C" void kernel_launch(void* const* d_in, const int* in_sizes, int n_in,
                              void* d_out, int out_size, void* d_ws, size_t ws_size,
                              hipStream_t stream) {
    const float* x   = (const float*)d_in[0];
    const int* ei    = (const int*)d_in[1];
    const int* batch = (const int*)d_in[2];
    const float* W0  = (const float*)d_in[3];
    const float* b0  = (const float*)d_in[4];
    const float* W1  = (const float*)d_in[5];
    const float* b1  = (const float*)d_in[6];
    const float* W2  = (const float*)d_in[7];
    const float* b2  = (const float*)d_in[8];
    const float* lw  = (const float*)d_in[9];
    const float* lb  = (const float*)d_in[10];
    float* out = (float*)d_out;

    const int N = in_sizes[2];        // 50000
    const int E = in_sizes[1] / 2;    // 600000
    const int G = 128;

    char* ws = (char*)d_ws;
    size_t off = 0;
    auto alloc = [&](size_t bytes) -> void* {
        void* p = ws + off;
        off += (bytes + 255) & ~(size_t)255;
        return p;
    };
    // common buffers
    float*  hA     = (float*) alloc((size_t)N * 128 * 4);
    float*  hB     = (float*) alloc((size_t)N * 128 * 4);
    __half* hBh    = (__half*)alloc((size_t)N * 128 * 2);
    float*  dinv   = (float*) alloc((size_t)N * 4);
    int*    cnt    = (int*)   alloc((size_t)N * 4);
    int*    rp     = (int*)   alloc((size_t)(N + 1) * 4);
    int*    bsum   = (int*)   alloc(1024 * 4);
    float*  pooled = (float*) alloc((size_t)G * 128 * 4);
    float*  gcnt   = (float*) alloc((size_t)G * 4);
    int*    gstart = (int*)   alloc((size_t)(G + 1) * 4);
    int2*   epack  = (int2*)  alloc((size_t)E * 8);     // fallback packets / reused
    // two-phase extras
    int*    cnt2   = (int*)   alloc((size_t)N * 4);
    int*    srp    = (int*)   alloc((size_t)(N + 1) * 4);
    int*    dpos   = (int*)   alloc((size_t)E * 4);
    int2*   sdata  = (int2*)  alloc((size_t)E * 8);
    __half* eval   = (__half*)alloc((size_t)E * 128 * 2);
    bool two_phase = (off <= ws_size);
    (void)n_in; (void)out_size;

    int nbN = (N + THREADS - 1) / THREADS;  // 196 (<=256 for k_scan2)
    int nbE = (E + THREADS - 1) / THREADS;
    int gemm_grid = (N + BM - 1) / BM;
    int node_grid = (N + 3) / 4;

    hipMemsetAsync(cnt, 0, (size_t)N * 4, stream);
    hipMemsetAsync(pooled, 0, (size_t)G * 128 * 4, stream);

    k_count_dst<<<nbE, THREADS, 0, stream>>>(ei, cnt, E);
    k_dinv<<<nbN, THREADS, 0, stream>>>(cnt, dinv, N);
    k_scan1<<<nbN, THREADS, 0, stream>>>(cnt, rp, bsum, N);
    k_scan2<<<1, THREADS, 0, stream>>>(bsum, nbN);
    k_add<<<nbN, THREADS, 0, stream>>>(rp, bsum, N, E);
    hipMemsetAsync(cnt, 0, (size_t)N * 4, stream);   // reuse as fill

    k_ginit<<<1, 128, 0, stream>>>(gstart, N, G);
    k_gbound<<<nbN, THREADS, 0, stream>>>(batch, gstart, N);
    k_gfix<<<1, 128, 0, stream>>>(gstart, gcnt, N, G);

    if (two_phase) {
        k_scatter_d<<<nbE, THREADS, 0, stream>>>(ei, rp, cnt, dpos, E);
        hipMemsetAsync(cnt2, 0, (size_t)N * 4, stream);
        k_count_src<<<nbE, THREADS, 0, stream>>>(ei, cnt2, E);
        k_scan1<<<nbN, THREADS, 0, stream>>>(cnt2, srp, bsum, N);
        k_scan2<<<1, THREADS, 0, stream>>>(bsum, nbN);
        k_add<<<nbN, THREADS, 0, stream>>>(srp, bsum, N, E);
        hipMemsetAsync(cnt2, 0, (size_t)N * 4, stream);
        k_scatter_s<<<nbE, THREADS, 0, stream>>>(ei, srp, cnt2, dinv, dpos, sdata, E);

        k_gemm<<<gemm_grid, 256, 0, stream>>>(x, W0, hB, hBh, N);
        k_phaseA<<<node_grid, 256, 0, stream>>>(hBh, srp, sdata, eval, N);
        k_phaseB<0><<<node_grid, 256, 0, stream>>>(hB, eval, hA, rp, dinv, b0, batch, pooled, N);
        k_gemm<<<gemm_grid, 256, 0, stream>>>(hA, W1, hB, hBh, N);
        k_phaseA<<<node_grid, 256, 0, stream>>>(hBh, srp, sdata, eval, N);
        k_phaseB<0><<<node_grid, 256, 0, stream>>>(hB, eval, hA, rp, dinv, b1, batch, pooled, N);
        k_gemm<<<gemm_grid, 256, 0, stream>>>(hA, W2, hB, hBh, N);
        k_phaseA<<<node_grid, 256, 0, stream>>>(hBh, srp, sdata, eval, N);
        k_phaseB<1><<<node_grid, 256, 0, stream>>>(hB, eval, hA, rp, dinv, b2, batch, pooled, N);
    } else {
        k_scatter_e<<<nbE, THREADS, 0, stream>>>(ei, rp, cnt, dinv, epack, E);

        k_gemm<<<gemm_grid, 256, 0, stream>>>(x, W0, hB, hBh, N);
        k_aggregate<0><<<node_grid, 256, 0, stream>>>(hB, hBh, hA, rp, epack, dinv, b0, batch, pooled, N);
        k_gemm<<<gemm_grid, 256, 0, stream>>>(hA, W1, hB, hBh, N);
        k_aggregate<0><<<node_grid, 256, 0, stream>>>(hB, hBh, hA, rp, epack, dinv, b1, batch, pooled, N);
        k_gemm<<<gemm_grid, 256, 0, stream>>>(hA, W2, hB, hBh, N);
        k_aggregate<1><<<node_grid, 256, 0, stream>>>(hB, hBh, hA, rp, epack, dinv, b2, batch, pooled, N);
    }

    k_final<<<(G * 64 + THREADS - 1) / THREADS, THREADS, 0, stream>>>(pooled, gcnt, lw, lb, out, G);
}